// Round 1
// baseline (106.218 us; speedup 1.0000x reference)
//
#include <hip/hip_runtime.h>
#include <stdint.h>

// Problem constants (from reference setup_inputs / module constants)
#define NB 32
#define NM 80
#define NT 2000
#define MSEL 16
#define NWIN 128         // 64 windows of w=5 + 64 windows of w=10
#define NBLK (NB * MSEL) // 512
#define NCOLS 2048.0f    // MSEL * 64 * 2 window lengths

struct Params {
    int mel[MSEL];
    int start[NWIN];     // [0:64) -> w=5 starts, [64:128) -> w=10 starts
};

// Module-static partials + completion counter (NOT the harness d_ws, which is
// poison-filled each iteration). Counter uses the mod-512 trick so it never
// needs resetting: the block whose atomicAdd returns old%512==511 is the last
// block of the current dispatch, across graph replays and rocprof replays.
__device__ float2   g_part[NBLK];
__device__ unsigned g_cnt = 0;

template <int W>
__device__ inline void win_acc(const float* __restrict__ sA,
                               const float* __restrict__ sP,
                               int s, const float* sK, const float* sSA,
                               const float* sSP,
                               float& dot, float& na, float& npv)
{
    #pragma unroll
    for (int t = 0; t < W; ++t) {
        float a = sA[s + t];
        float p = sP[s + t];
        int ia = (a >= 0.f) ? 1 : 0;
        int ip = (p >= 0.f) ? 1 : 0;
        dot += a * p * sK[ia * 2 + ip];
        na  += a * a * sSA[ia];
        npv += p * p * sSP[ip];
    }
}

// ---------------------------------------------------------------------------
// Fused kernel: one block per (b, mel_sel). Stage both rows to LDS, each
// thread computes one window's cosine distance via the collapsed-head
// formulation, block reduces to (sum_D, sum_relu(margin-D)) -> g_part[blk].
// Last block (device-scope counter) performs the 512 -> 33 final reduction
// and writes out[0]=stc_loss, out[1..32]=coh_score[b].
// ---------------------------------------------------------------------------
__global__ __launch_bounds__(128) void asn_fused_kernel(
    const float* __restrict__ A, const float* __restrict__ P,
    const float* __restrict__ W1a, const float* __restrict__ W2a,
    const float* __restrict__ W1p, const float* __restrict__ W2p,
    const int* __restrict__ y, float* __restrict__ out, Params prm)
{
    __shared__ float4 sA4[NT / 4];
    __shared__ float4 sP4[NT / 4];
    __shared__ float sK[4];      // K[ia*2+ip], ia/ip: 1 = value >= 0
    __shared__ float sSA[2];
    __shared__ float sSP[2];
    __shared__ float wsum[2][2];
    __shared__ int   s_last;

    float* sA = (float*)sA4;
    float* sP = (float*)sP4;

    const int blk = blockIdx.x;      // 0..511
    const int b   = blk >> 4;
    const int msi = blk & 15;
    const int m   = prm.mel[msi];
    const int tid = threadIdx.x;

    if (tid == 0) {
        // Collapsed head coefficients:
        //   head(a)[o] = a * (a>=0 ? cap[o] : can[o])
        // cap[o] = sum_{c: W1[c]>0} W1[c]*W2[o,c];  can: W1[c]<0 terms.
        float cap[8], can[8], cqp[8], cqn[8];
        #pragma unroll
        for (int o = 0; o < 8; ++o) { cap[o]=0.f; can[o]=0.f; cqp[o]=0.f; cqn[o]=0.f; }
        #pragma unroll
        for (int c = 0; c < 8; ++c) {
            float wa = W1a[c], wp = W1p[c];
            #pragma unroll
            for (int o = 0; o < 8; ++o) {
                float ta = wa * W2a[o * 8 + c];
                float tp = wp * W2p[o * 8 + c];
                if (wa > 0.f) cap[o] += ta; else if (wa < 0.f) can[o] += ta;
                if (wp > 0.f) cqp[o] += tp; else if (wp < 0.f) cqn[o] += tp;
            }
        }
        float kpp=0.f,kpn=0.f,knp=0.f,knn=0.f,sap=0.f,san=0.f,spp=0.f,spn=0.f;
        #pragma unroll
        for (int o = 0; o < 8; ++o) {
            kpp += cap[o]*cqp[o];  kpn += cap[o]*cqn[o];
            knp += can[o]*cqp[o];  knn += can[o]*cqn[o];
            sap += cap[o]*cap[o];  san += can[o]*can[o];
            spp += cqp[o]*cqp[o];  spn += cqn[o]*cqn[o];
        }
        sK[3]=kpp; sK[2]=kpn; sK[1]=knp; sK[0]=knn;
        sSA[1]=sap; sSA[0]=san;
        sSP[1]=spp; sSP[0]=spn;
    }

    // Stage the two selected rows (contiguous, 16B-aligned: row = 8000 B)
    const float4* arow = (const float4*)(A + ((size_t)b * NM + m) * NT);
    const float4* prow = (const float4*)(P + ((size_t)b * NM + m) * NT);
    for (int t = tid; t < NT / 4; t += 128) {
        sA4[t] = arow[t];
        sP4[t] = prow[t];
    }
    __syncthreads();

    // One window per thread (wave0: w=5, wave1: w=10 -- wave-uniform branch)
    const int s = prm.start[tid];
    float dot = 0.f, na = 0.f, npv = 0.f;
    if (tid < 64) win_acc<5> (sA, sP, s, sK, sSA, sSP, dot, na, npv);
    else          win_acc<10>(sA, sP, s, sK, sSA, sSP, dot, na, npv);

    float nu = fmaxf(sqrtf(na),  1e-12f);
    float nv = fmaxf(sqrtf(npv), 1e-12f);
    float dist = 1.f - dot / (nu * nv);
    float rd   = fmaxf(0.2f - dist, 0.f);   // relu(MARGIN - D)

    // reduce 128 threads -> 2 values
    float s1 = dist, s2 = rd;
    #pragma unroll
    for (int off = 32; off; off >>= 1) {
        s1 += __shfl_down(s1, off);
        s2 += __shfl_down(s2, off);
    }
    if ((tid & 63) == 0) {
        wsum[tid >> 6][0] = s1;
        wsum[tid >> 6][1] = s2;
    }
    __syncthreads();

    if (tid == 0) {
        float2 v = make_float2(wsum[0][0] + wsum[1][0],
                               wsum[0][1] + wsum[1][1]);
        g_part[blk] = v;
        __threadfence();                       // release g_part write
        unsigned old = atomicAdd(&g_cnt, 1u);  // device-scope
        s_last = ((old & (NBLK - 1)) == (NBLK - 1)) ? 1 : 0;
    }
    __syncthreads();
    if (!s_last) return;

    // ---------------- last block: final reduction (512 -> 33) --------------
    __threadfence();                           // acquire all g_part writes

    float* sD = sA;                            // reuse LDS (block is past use)
    float aR = 0.f, aS = 0.f;
    #pragma unroll
    for (int r = 0; r < 4; ++r) {
        int k = r * 128 + tid;                 // 0..511
        float2 v = g_part[k];
        sD[k] = v.x;                           // sumD, for coh_score
        if (y[k >> 4] == 0) aR += v.x; else aS += v.y;
    }
    #pragma unroll
    for (int off = 32; off; off >>= 1) {
        aR += __shfl_down(aR, off);
        aS += __shfl_down(aS, off);
    }
    if ((tid & 63) == 0) {
        wsum[tid >> 6][0] = aR;
        wsum[tid >> 6][1] = aS;
    }
    __syncthreads();

    // coh_score[b]: batch bb covers k in [16*bb, 16*bb+16)
    if (tid < NB) {
        float v = 0.f;
        #pragma unroll
        for (int i = 0; i < 16; ++i) v += sD[tid * 16 + i];
        out[1 + tid] = 1.f - v * (1.0f / NCOLS);
    }
    if (tid == 0) {
        int nr = 0, ns = 0;
        for (int bb = 0; bb < NB; ++bb) { int yb = y[bb]; nr += (yb == 0); ns += (yb == 1); }
        float aRt = wsum[0][0] + wsum[1][0];
        float aSt = wsum[0][1] + wsum[1][1];
        float lr = aRt / (NCOLS * (float)(nr > 0 ? nr : 1));
        float ls = aSt / (NCOLS * (float)(ns > 0 ? ns : 1));
        out[0] = lr + 0.5f * ls;               // stc_loss
    }
}

// ---------------------------------------------------------------------------
// Host: bit-exact replication of np.random.default_rng(123).permutation(80)
// (SeedSequence -> PCG64 XSL-RR 128/64 -> random_interval Fisher-Yates)
// and of np.linspace(...).astype(int64) window-start subsampling.
// Pure CPU work, deterministic, graph-capture safe.
// ---------------------------------------------------------------------------
static void compute_params(Params& prm)
{
    // ---- numpy SeedSequence(123) ----
    const uint32_t INIT_A = 0x43b0d7e5u, MULT_A = 0x931e8875u;
    const uint32_t INIT_B = 0x8b51f9ddu, MULT_B = 0x58f38dedu;

    uint32_t hc = INIT_A;
    auto hashmix = [&](uint32_t v) -> uint32_t {
        v ^= hc; hc *= MULT_A; v *= hc; v ^= v >> 16; return v;
    };
    auto mix = [](uint32_t x, uint32_t y) -> uint32_t {
        uint32_t r = (x * 0xca01f9ddu) ^ (y * 0x4973f715u);
        r ^= r >> 16; return r;
    };

    uint32_t pool[4];
    const uint32_t entropy[1] = { 123u };
    for (int i = 0; i < 4; ++i) pool[i] = hashmix(i < 1 ? entropy[i] : 0u);
    for (int s = 0; s < 4; ++s)
        for (int d = 0; d < 4; ++d)
            if (s != d) pool[d] = mix(pool[d], hashmix(pool[s]));

    // generate_state(4, uint64) -> 8 uint32 words, LE-paired
    uint32_t w32[8];
    uint32_t hc2 = INIT_B;
    for (int i = 0; i < 8; ++i) {
        uint32_t v = pool[i & 3];
        v ^= hc2; hc2 *= MULT_B; v ^= 0u; v *= hc2; v ^= v >> 16;
        w32[i] = v;
    }
    uint64_t sd[4];
    for (int i = 0; i < 4; ++i)
        sd[i] = (uint64_t)w32[2 * i] | ((uint64_t)w32[2 * i + 1] << 32);

    // ---- PCG64 (setseq 128, XSL-RR output) ----
    typedef __uint128_t u128;
    const u128 MULT = ((u128)0x2360ed051fc65da4ULL << 64) | 0x4385df649fccf645ULL;
    u128 initstate = ((u128)sd[0] << 64) | sd[1];
    u128 initseq   = ((u128)sd[2] << 64) | sd[3];
    u128 state = 0, inc = (initseq << 1) | 1;
    state = state * MULT + inc;
    state += initstate;
    state = state * MULT + inc;

    bool has32 = false; uint32_t buf32 = 0;
    auto next64 = [&]() -> uint64_t {
        state = state * MULT + inc;                 // step THEN output
        uint64_t hi = (uint64_t)(state >> 64);
        uint64_t lo = (uint64_t)state;
        uint64_t x = hi ^ lo;
        unsigned rot = (unsigned)(state >> 122);    // top 6 bits
        return (x >> rot) | (x << ((64u - rot) & 63u));
    };
    auto next32 = [&]() -> uint32_t {
        if (has32) { has32 = false; return buf32; }
        uint64_t v = next64();
        has32 = true; buf32 = (uint32_t)(v >> 32);  // high half buffered
        return (uint32_t)v;                          // low half first
    };

    // ---- Generator.permutation(80): Fisher-Yates with random_interval ----
    int perm[NM];
    for (int i = 0; i < NM; ++i) perm[i] = i;
    for (int i = NM - 1; i >= 1; --i) {
        uint32_t mask = (uint32_t)i;
        mask |= mask >> 1; mask |= mask >> 2; mask |= mask >> 4;
        mask |= mask >> 8; mask |= mask >> 16;
        uint32_t j;
        do { j = next32() & mask; } while (j > (uint32_t)i);
        int tmp = perm[i]; perm[i] = perm[(int)j]; perm[(int)j] = tmp;
    }
    for (int i = 0; i < MSEL; ++i) prm.mel[i] = perm[i];

    // ---- window starts ----
    // hop_frames=3. w=5: full starts 0..1995 step 3 (666) -> linspace(0,665,64)
    //               w=10: full starts 0..1989 step 3 (664) -> linspace(0,663,64)
    {
        const double step = 665.0 / 63.0;
        for (int i = 0; i < 64; ++i) {
            long long sel = (i == 63) ? 665LL : (long long)((double)i * step);
            prm.start[i] = (int)(3LL * sel);
        }
    }
    {
        const double step = 663.0 / 63.0;
        for (int i = 0; i < 64; ++i) {
            long long sel = (i == 63) ? 663LL : (long long)((double)i * step);
            prm.start[64 + i] = (int)(3LL * sel);
        }
    }
}

extern "C" void kernel_launch(void* const* d_in, const int* in_sizes, int n_in,
                              void* d_out, int out_size, void* d_ws, size_t ws_size,
                              hipStream_t stream)
{
    const float* A   = (const float*)d_in[0];
    const float* P   = (const float*)d_in[1];
    const int*   y   = (const int*)d_in[2];
    const float* W1a = (const float*)d_in[3];
    const float* W2a = (const float*)d_in[4];
    const float* W1p = (const float*)d_in[5];
    const float* W2p = (const float*)d_in[6];
    float* out = (float*)d_out;
    (void)d_ws; (void)ws_size;   // harness workspace intentionally unused

    Params prm;
    compute_params(prm);

    asn_fused_kernel<<<dim3(NBLK), dim3(128), 0, stream>>>(
        A, P, W1a, W2a, W1p, W2p, y, out, prm);
}

// Round 2
// 96.115 us; speedup vs baseline: 1.1051x; 1.1051x over previous
//
#include <hip/hip_runtime.h>
#include <stdint.h>

// Problem constants (from reference setup_inputs / module constants)
#define NB 32
#define NM 80
#define NT 2000
#define MSEL 16
#define NWIN 128         // 64 windows of w=5 + 64 windows of w=10
#define NBLK (NB * MSEL) // 512
#define NCOLS 2048.0f    // MSEL * 64 * 2 window lengths

struct Params {
    int mel[MSEL];
    int start[NWIN];     // [0:64) -> w=5 starts, [64:128) -> w=10 starts
};

// Module-static intermediates (NOT harness d_ws, which is poison-filled and
// would serialize us behind the 256-MiB fill).
// g_coef[0] = (knn, knp, kpn, kpp)   K by (sign a, sign p)
// g_coef[1] = (san, sap, spn, spp)   norm coefs by sign
__device__ float4 g_coef[2];
__device__ float2 g_part[NBLK];

// ---------------------------------------------------------------------------
// Kernel 0 (1 wave, runs once): collapse the 1->8->8 ReLU head into 8 scalars.
// Replaces the per-block serial tid==0 section (~144 serialized scalar loads
// on one lane, ~20-50 us per block) with 64 PARALLEL lane loads + shuffle
// reductions (~1-2 us, once per launch).
//
//   head(x)[o] = x * (x>=0 ? cap[o] : can[o]),
//   cap[o] = sum_{c: W1[c]>0} W1[c]*W2[o,c];  can: W1[c]<0 terms.
//   K(sa,sp) = sum_o ca[o]*cq[o];  norms use sum_o ca[o]^2 / cq[o]^2.
// ---------------------------------------------------------------------------
__global__ __launch_bounds__(64) void asn_coef_kernel(
    const float* __restrict__ W1a, const float* __restrict__ W2a,
    const float* __restrict__ W1p, const float* __restrict__ W2p)
{
    const int i = threadIdx.x;   // 0..63, maps to W2 element (o = i>>3, c = i&7)
    const int c = i & 7;

    // 64 parallel loads per array (W2), 8 for W1 -- one memory latency total.
    float w2a = W2a[i];
    float w2p = W2p[i];
    float w1a_l = (i < 8) ? W1a[i] : 0.f;
    float w1p_l = (i < 8) ? W1p[i] : 0.f;
    float wa = __shfl(w1a_l, c);          // W1a[c] broadcast to all o-groups
    float wp = __shfl(w1p_l, c);

    float ta = wa * w2a, tp = wp * w2p;
    float cap = (wa > 0.f) ? ta : 0.f;
    float can = (wa < 0.f) ? ta : 0.f;
    float cqp = (wp > 0.f) ? tp : 0.f;
    float cqn = (wp < 0.f) ? tp : 0.f;

    // Sum over c within each 8-lane o-group.
    #pragma unroll
    for (int off = 1; off < 8; off <<= 1) {
        cap += __shfl_xor(cap, off);
        can += __shfl_xor(can, off);
        cqp += __shfl_xor(cqp, off);
        cqn += __shfl_xor(cqn, off);
    }

    // Per-o products on the group representative (c==0), then sum over o.
    const bool rep = (c == 0);
    float q0 = rep ? can * cqn : 0.f;   // knn
    float q1 = rep ? can * cqp : 0.f;   // knp
    float q2 = rep ? cap * cqn : 0.f;   // kpn
    float q3 = rep ? cap * cqp : 0.f;   // kpp
    float q4 = rep ? can * can : 0.f;   // san
    float q5 = rep ? cap * cap : 0.f;   // sap
    float q6 = rep ? cqn * cqn : 0.f;   // spn
    float q7 = rep ? cqp * cqp : 0.f;   // spp
    #pragma unroll
    for (int off = 8; off < 64; off <<= 1) {
        q0 += __shfl_xor(q0, off);
        q1 += __shfl_xor(q1, off);
        q2 += __shfl_xor(q2, off);
        q3 += __shfl_xor(q3, off);
        q4 += __shfl_xor(q4, off);
        q5 += __shfl_xor(q5, off);
        q6 += __shfl_xor(q6, off);
        q7 += __shfl_xor(q7, off);
    }
    if (i == 0) {
        g_coef[0] = make_float4(q0, q1, q2, q3);
        g_coef[1] = make_float4(q4, q5, q6, q7);
    }
}

template <int W>
__device__ inline void win_acc(const float* __restrict__ sA,
                               const float* __restrict__ sP,
                               int s, float4 c0, float4 c1,
                               float& dot, float& na, float& npv)
{
    #pragma unroll
    for (int t = 0; t < W; ++t) {
        float a = sA[s + t];
        float p = sP[s + t];
        // register selects (v_cndmask), no LDS gather
        float k  = (a >= 0.f) ? ((p >= 0.f) ? c0.w : c0.z)
                              : ((p >= 0.f) ? c0.y : c0.x);
        float sa = (a >= 0.f) ? c1.y : c1.x;
        float sp = (p >= 0.f) ? c1.w : c1.z;
        dot += a * p * k;
        na  += a * a * sa;
        npv += p * p * sp;
    }
}

// ---------------------------------------------------------------------------
// Kernel 1: one block per (b, mel_sel). Stage both rows to LDS, each thread
// computes one window's cosine distance via the collapsed-head coefficients,
// block reduces to (sum_D, sum_relu(margin-D)) -> g_part[blk]. Plain stores;
// no fences/atomics (the 512-way same-address atomic tail cost ~40 us in r1).
// ---------------------------------------------------------------------------
__global__ __launch_bounds__(128) void asn_win_kernel(
    const float* __restrict__ A, const float* __restrict__ P, Params prm)
{
    __shared__ float4 sA4[NT / 4];
    __shared__ float4 sP4[NT / 4];
    __shared__ float wsum[2][2];

    const float* sA = (const float*)sA4;
    const float* sP = (const float*)sP4;

    const int blk = blockIdx.x;      // 0..511
    const int b   = blk >> 4;
    const int msi = blk & 15;
    const int m   = prm.mel[msi];
    const int tid = threadIdx.x;

    // Stage the two selected rows (contiguous, 16B-aligned: row = 8000 B)
    const float4* arow = (const float4*)(A + ((size_t)b * NM + m) * NT);
    const float4* prow = (const float4*)(P + ((size_t)b * NM + m) * NT);
    for (int t = tid; t < NT / 4; t += 128) {
        sA4[t] = arow[t];
        sP4[t] = prow[t];
    }

    // Collapsed-head coefficients: 2 x 16B broadcast loads (L2-hot)
    const float4 c0 = g_coef[0];
    const float4 c1 = g_coef[1];

    __syncthreads();

    // One window per thread (wave0: w=5, wave1: w=10 -- wave-uniform branch)
    const int s = prm.start[tid];
    float dot = 0.f, na = 0.f, npv = 0.f;
    if (tid < 64) win_acc<5> (sA, sP, s, c0, c1, dot, na, npv);
    else          win_acc<10>(sA, sP, s, c0, c1, dot, na, npv);

    float nu = fmaxf(sqrtf(na),  1e-12f);
    float nv = fmaxf(sqrtf(npv), 1e-12f);
    float dist = 1.f - dot / (nu * nv);
    float rd   = fmaxf(0.2f - dist, 0.f);   // relu(MARGIN - D)

    // reduce 128 threads -> 2 values
    float s1 = dist, s2 = rd;
    #pragma unroll
    for (int off = 32; off; off >>= 1) {
        s1 += __shfl_down(s1, off);
        s2 += __shfl_down(s2, off);
    }
    if ((tid & 63) == 0) {
        wsum[tid >> 6][0] = s1;
        wsum[tid >> 6][1] = s2;
    }
    __syncthreads();
    if (tid == 0) {
        g_part[blk] = make_float2(wsum[0][0] + wsum[1][0],
                                  wsum[0][1] + wsum[1][1]);
    }
}

// ---------------------------------------------------------------------------
// Kernel 2: one wave (64 threads), no LDS, pure shuffle reduction.
// out[0]=stc_loss, out[1..32]=coh_score[b]. Cross-dispatch visibility of
// g_part is guaranteed by same-stream ordering (runtime cache maintenance).
// ---------------------------------------------------------------------------
__global__ __launch_bounds__(64) void asn_final_kernel(
    const int* __restrict__ y, float* __restrict__ out)
{
    const int tid = threadIdx.x;

    // Each lane accumulates 8 of the 512 partial pairs (strided, coalesced)
    float aR = 0.f, aS = 0.f;
    float colsum[8];                 // per-lane contribution to coh per group
    #pragma unroll
    for (int r = 0; r < 8; ++r) {
        int k  = r * 64 + tid;       // 0..511
        int bb = k >> 4;
        float2 v = g_part[k];
        if (y[bb] == 0) aR += v.x; else aS += v.y;
        colsum[r] = v.x;
    }
    // wave-reduce the masked loss sums
    #pragma unroll
    for (int off = 32; off; off >>= 1) {
        aR += __shfl_down(aR, off);
        aS += __shfl_down(aS, off);
    }

    // coh_score: b = k>>4, so batch bb spans k in [16*bb, 16*bb+16).
    // Lane layout: k = r*64 + tid -> batch bb = r*4 + (tid>>4), reduce within
    // each 16-lane group.
    #pragma unroll
    for (int r = 0; r < 8; ++r) {
        float v = colsum[r];
        #pragma unroll
        for (int off = 8; off; off >>= 1) v += __shfl_down(v, off);
        if ((tid & 15) == 0) {
            int bb = r * 4 + (tid >> 4);
            out[1 + bb] = 1.f - v * (1.0f / NCOLS);
        }
    }

    if (tid == 0) {
        int nr = 0, ns = 0;
        for (int bb = 0; bb < NB; ++bb) { int yb = y[bb]; nr += (yb == 0); ns += (yb == 1); }
        float lr = aR / (NCOLS * (float)(nr > 0 ? nr : 1));
        float ls = aS / (NCOLS * (float)(ns > 0 ? ns : 1));
        out[0] = lr + 0.5f * ls;                     // stc_loss
    }
}

// ---------------------------------------------------------------------------
// Host: bit-exact replication of np.random.default_rng(123).permutation(80)
// (SeedSequence -> PCG64 XSL-RR 128/64 -> random_interval Fisher-Yates)
// and of np.linspace(...).astype(int64) window-start subsampling.
// Pure CPU work, deterministic, graph-capture safe.
// ---------------------------------------------------------------------------
static void compute_params(Params& prm)
{
    // ---- numpy SeedSequence(123) ----
    const uint32_t INIT_A = 0x43b0d7e5u, MULT_A = 0x931e8875u;
    const uint32_t INIT_B = 0x8b51f9ddu, MULT_B = 0x58f38dedu;

    uint32_t hc = INIT_A;
    auto hashmix = [&](uint32_t v) -> uint32_t {
        v ^= hc; hc *= MULT_A; v *= hc; v ^= v >> 16; return v;
    };
    auto mix = [](uint32_t x, uint32_t y) -> uint32_t {
        uint32_t r = (x * 0xca01f9ddu) ^ (y * 0x4973f715u);
        r ^= r >> 16; return r;
    };

    uint32_t pool[4];
    const uint32_t entropy[1] = { 123u };
    for (int i = 0; i < 4; ++i) pool[i] = hashmix(i < 1 ? entropy[i] : 0u);
    for (int s = 0; s < 4; ++s)
        for (int d = 0; d < 4; ++d)
            if (s != d) pool[d] = mix(pool[d], hashmix(pool[s]));

    // generate_state(4, uint64) -> 8 uint32 words, LE-paired
    uint32_t w32[8];
    uint32_t hc2 = INIT_B;
    for (int i = 0; i < 8; ++i) {
        uint32_t v = pool[i & 3];
        v ^= hc2; hc2 *= MULT_B; v *= hc2; v ^= v >> 16;
        w32[i] = v;
    }
    uint64_t sd[4];
    for (int i = 0; i < 4; ++i)
        sd[i] = (uint64_t)w32[2 * i] | ((uint64_t)w32[2 * i + 1] << 32);

    // ---- PCG64 (setseq 128, XSL-RR output) ----
    typedef __uint128_t u128;
    const u128 MULT = ((u128)0x2360ed051fc65da4ULL << 64) | 0x4385df649fccf645ULL;
    u128 initstate = ((u128)sd[0] << 64) | sd[1];
    u128 initseq   = ((u128)sd[2] << 64) | sd[3];
    u128 state = 0, inc = (initseq << 1) | 1;
    state = state * MULT + inc;
    state += initstate;
    state = state * MULT + inc;

    bool has32 = false; uint32_t buf32 = 0;
    auto next64 = [&]() -> uint64_t {
        state = state * MULT + inc;                 // step THEN output
        uint64_t hi = (uint64_t)(state >> 64);
        uint64_t lo = (uint64_t)state;
        uint64_t x = hi ^ lo;
        unsigned rot = (unsigned)(state >> 122);    // top 6 bits
        return (x >> rot) | (x << ((64u - rot) & 63u));
    };
    auto next32 = [&]() -> uint32_t {
        if (has32) { has32 = false; return buf32; }
        uint64_t v = next64();
        has32 = true; buf32 = (uint32_t)(v >> 32);  // high half buffered
        return (uint32_t)v;                          // low half first
    };

    // ---- Generator.permutation(80): Fisher-Yates with random_interval ----
    int perm[NM];
    for (int i = 0; i < NM; ++i) perm[i] = i;
    for (int i = NM - 1; i >= 1; --i) {
        uint32_t mask = (uint32_t)i;
        mask |= mask >> 1; mask |= mask >> 2; mask |= mask >> 4;
        mask |= mask >> 8; mask |= mask >> 16;
        uint32_t j;
        do { j = next32() & mask; } while (j > (uint32_t)i);
        int tmp = perm[i]; perm[i] = perm[(int)j]; perm[(int)j] = tmp;
    }
    for (int i = 0; i < MSEL; ++i) prm.mel[i] = perm[i];

    // ---- window starts ----
    // hop_frames=3. w=5: full starts 0..1995 step 3 (666) -> linspace(0,665,64)
    //               w=10: full starts 0..1989 step 3 (664) -> linspace(0,663,64)
    {
        const double step = 665.0 / 63.0;
        for (int i = 0; i < 64; ++i) {
            long long sel = (i == 63) ? 665LL : (long long)((double)i * step);
            prm.start[i] = (int)(3LL * sel);
        }
    }
    {
        const double step = 663.0 / 63.0;
        for (int i = 0; i < 64; ++i) {
            long long sel = (i == 63) ? 663LL : (long long)((double)i * step);
            prm.start[64 + i] = (int)(3LL * sel);
        }
    }
}

extern "C" void kernel_launch(void* const* d_in, const int* in_sizes, int n_in,
                              void* d_out, int out_size, void* d_ws, size_t ws_size,
                              hipStream_t stream)
{
    const float* A   = (const float*)d_in[0];
    const float* P   = (const float*)d_in[1];
    const int*   y   = (const int*)d_in[2];
    const float* W1a = (const float*)d_in[3];
    const float* W2a = (const float*)d_in[4];
    const float* W1p = (const float*)d_in[5];
    const float* W2p = (const float*)d_in[6];
    float* out = (float*)d_out;
    (void)d_ws; (void)ws_size;   // harness workspace intentionally unused

    Params prm;
    compute_params(prm);

    asn_coef_kernel<<<dim3(1), dim3(64), 0, stream>>>(W1a, W2a, W1p, W2p);
    asn_win_kernel<<<dim3(NBLK), dim3(128), 0, stream>>>(A, P, prm);
    asn_final_kernel<<<dim3(1), dim3(64), 0, stream>>>(y, out);
}

// Round 3
// 94.824 us; speedup vs baseline: 1.1202x; 1.0136x over previous
//
#include <hip/hip_runtime.h>
#include <stdint.h>

// Problem constants (from reference setup_inputs / module constants)
#define NB 32
#define NM 80
#define NT 2000
#define MSEL 16
#define NWIN 128         // 64 windows of w=5 + 64 windows of w=10
#define NBLK (NB * MSEL) // 512
#define NCOLS 2048.0f    // MSEL * 64 * 2 window lengths

struct Params {
    int mel[MSEL];
    int start[NWIN];     // [0:64) -> w=5 starts, [64:128) -> w=10 starts
};

// Module-static intermediate (NOT harness d_ws, which is poison-filled each
// iteration and would serialize us behind the 256-MiB fill).
__device__ float2 g_part[NBLK];

template <int W>
__device__ inline void win_acc(const float* __restrict__ sA,
                               const float* __restrict__ sP,
                               int s, float4 c0, float4 c1,
                               float& dot, float& na, float& npv)
{
    #pragma unroll
    for (int t = 0; t < W; ++t) {
        float a = sA[s + t];
        float p = sP[s + t];
        // register selects (v_cndmask), no LDS gather
        float k  = (a >= 0.f) ? ((p >= 0.f) ? c0.w : c0.z)
                              : ((p >= 0.f) ? c0.y : c0.x);
        float sa = (a >= 0.f) ? c1.y : c1.x;
        float sp = (p >= 0.f) ? c1.w : c1.z;
        dot += a * p * k;
        na  += a * a * sa;
        npv += p * p * sp;
    }
}

// ---------------------------------------------------------------------------
// Kernel 1: one block per (b, mel_sel).
//  - wave 0 collapses the 1->8->8 ReLU head into 8 scalars with 64 PARALLEL
//    lane loads + shuffle reductions (overlaps wave 1's staging loads);
//    head(x)[o] = x * (x>=0 ? cap[o] : can[o]),
//    cap[o] = sum_{c: W1[c]>0} W1[c]*W2[o,c];  can: W1[c]<0 terms.
//  - all threads stage the two selected rows to LDS (register-pipelined:
//    all global loads issued before any LDS write -> max MLP under the
//    harness fill's HBM contention);
//  - each thread computes one window's cosine distance; block reduces to
//    (sum_D, sum_relu(margin-D)) -> g_part[blk]. Plain stores, no atomics
//    (512-way same-address atomic tail measured ~+13 us in round 1).
// ---------------------------------------------------------------------------
__global__ __launch_bounds__(128) void asn_win_kernel(
    const float* __restrict__ A, const float* __restrict__ P,
    const float* __restrict__ W1a, const float* __restrict__ W2a,
    const float* __restrict__ W1p, const float* __restrict__ W2p,
    Params prm)
{
    __shared__ float4 sA4[NT / 4];
    __shared__ float4 sP4[NT / 4];
    __shared__ float4 sCoefV[2];   // [0]=(knn,knp,kpn,kpp) [1]=(san,sap,spn,spp)
    __shared__ float  wsum[2][2];

    const float* sA = (const float*)sA4;
    const float* sP = (const float*)sP4;

    const int blk = blockIdx.x;      // 0..511
    const int b   = blk >> 4;
    const int msi = blk & 15;
    const int m   = prm.mel[msi];
    const int tid = threadIdx.x;

    const float4* arow = (const float4*)(A + ((size_t)b * NM + m) * NT);
    const float4* prow = (const float4*)(P + ((size_t)b * NM + m) * NT);

    // ---- wave 0: parallel head-collapse (W arrays are tiny + L2-hot) ------
    if (tid < 64) {
        const int c = tid & 7;                 // o = tid>>3, c = tid&7
        float w2a = W2a[tid];
        float w2p = W2p[tid];
        float w1a_l = (tid < 8) ? W1a[tid] : 0.f;
        float w1p_l = (tid < 8) ? W1p[tid] : 0.f;
        float wa = __shfl(w1a_l, c);           // W1[c] broadcast to all o-groups
        float wp = __shfl(w1p_l, c);

        float ta = wa * w2a, tp = wp * w2p;
        float cap = (wa > 0.f) ? ta : 0.f;
        float can = (wa < 0.f) ? ta : 0.f;
        float cqp = (wp > 0.f) ? tp : 0.f;
        float cqn = (wp < 0.f) ? tp : 0.f;

        // sum over c within each 8-lane o-group
        #pragma unroll
        for (int off = 1; off < 8; off <<= 1) {
            cap += __shfl_xor(cap, off);
            can += __shfl_xor(can, off);
            cqp += __shfl_xor(cqp, off);
            cqn += __shfl_xor(cqn, off);
        }

        // per-o products on the group representative, then sum over o
        const bool rep = (c == 0);
        float q0 = rep ? can * cqn : 0.f;   // knn
        float q1 = rep ? can * cqp : 0.f;   // knp
        float q2 = rep ? cap * cqn : 0.f;   // kpn
        float q3 = rep ? cap * cqp : 0.f;   // kpp
        float q4 = rep ? can * can : 0.f;   // san
        float q5 = rep ? cap * cap : 0.f;   // sap
        float q6 = rep ? cqn * cqn : 0.f;   // spn
        float q7 = rep ? cqp * cqp : 0.f;   // spp
        #pragma unroll
        for (int off = 8; off < 64; off <<= 1) {
            q0 += __shfl_xor(q0, off);
            q1 += __shfl_xor(q1, off);
            q2 += __shfl_xor(q2, off);
            q3 += __shfl_xor(q3, off);
            q4 += __shfl_xor(q4, off);
            q5 += __shfl_xor(q5, off);
            q6 += __shfl_xor(q6, off);
            q7 += __shfl_xor(q7, off);
        }
        if (tid == 0) {
            sCoefV[0] = make_float4(q0, q1, q2, q3);
            sCoefV[1] = make_float4(q4, q5, q6, q7);
        }
    }

    // ---- staging: issue ALL global loads, then write LDS (max MLP) --------
    // t = tid, tid+128, tid+256, tid+384 (last guarded: only tid<116)
    {
        const int  t0 = tid, t1 = tid + 128, t2 = tid + 256, t3 = tid + 384;
        const bool g3 = (t3 < NT / 4);
        float4 a0 = arow[t0], p0 = prow[t0];
        float4 a1 = arow[t1], p1 = prow[t1];
        float4 a2 = arow[t2], p2 = prow[t2];
        float4 a3, p3;
        if (g3) { a3 = arow[t3]; p3 = prow[t3]; }
        sA4[t0] = a0;  sP4[t0] = p0;
        sA4[t1] = a1;  sP4[t1] = p1;
        sA4[t2] = a2;  sP4[t2] = p2;
        if (g3) { sA4[t3] = a3;  sP4[t3] = p3; }
    }

    __syncthreads();

    const float4 c0 = sCoefV[0];
    const float4 c1 = sCoefV[1];

    // One window per thread (wave0: w=5, wave1: w=10 -- wave-uniform branch)
    const int s = prm.start[tid];
    float dot = 0.f, na = 0.f, npv = 0.f;
    if (tid < 64) win_acc<5> (sA, sP, s, c0, c1, dot, na, npv);
    else          win_acc<10>(sA, sP, s, c0, c1, dot, na, npv);

    float nu = fmaxf(sqrtf(na),  1e-12f);
    float nv = fmaxf(sqrtf(npv), 1e-12f);
    float dist = 1.f - dot / (nu * nv);
    float rd   = fmaxf(0.2f - dist, 0.f);   // relu(MARGIN - D)

    // reduce 128 threads -> 2 values
    float s1 = dist, s2 = rd;
    #pragma unroll
    for (int off = 32; off; off >>= 1) {
        s1 += __shfl_down(s1, off);
        s2 += __shfl_down(s2, off);
    }
    if ((tid & 63) == 0) {
        wsum[tid >> 6][0] = s1;
        wsum[tid >> 6][1] = s2;
    }
    __syncthreads();
    if (tid == 0) {
        g_part[blk] = make_float2(wsum[0][0] + wsum[1][0],
                                  wsum[0][1] + wsum[1][1]);
    }
}

// ---------------------------------------------------------------------------
// Kernel 2: one wave (64 threads), no LDS, pure shuffle reduction.
// out[0]=stc_loss, out[1..32]=coh_score[b]. Cross-dispatch visibility of
// g_part is guaranteed by same-stream ordering (runtime cache maintenance).
// ---------------------------------------------------------------------------
__global__ __launch_bounds__(64) void asn_final_kernel(
    const int* __restrict__ y, float* __restrict__ out)
{
    const int tid = threadIdx.x;

    // Each lane accumulates 8 of the 512 partial pairs (strided, coalesced)
    float aR = 0.f, aS = 0.f;
    float colsum[8];                 // per-lane contribution to coh per group
    #pragma unroll
    for (int r = 0; r < 8; ++r) {
        int k  = r * 64 + tid;       // 0..511
        int bb = k >> 4;
        float2 v = g_part[k];
        if (y[bb] == 0) aR += v.x; else aS += v.y;
        colsum[r] = v.x;
    }
    // wave-reduce the masked loss sums
    #pragma unroll
    for (int off = 32; off; off >>= 1) {
        aR += __shfl_down(aR, off);
        aS += __shfl_down(aS, off);
    }

    // coh_score: b = k>>4, so batch bb spans k in [16*bb, 16*bb+16).
    // Lane layout: k = r*64 + tid -> batch bb = r*4 + (tid>>4), reduce within
    // each 16-lane group.
    #pragma unroll
    for (int r = 0; r < 8; ++r) {
        float v = colsum[r];
        #pragma unroll
        for (int off = 8; off; off >>= 1) v += __shfl_down(v, off);
        if ((tid & 15) == 0) {
            int bb = r * 4 + (tid >> 4);
            out[1 + bb] = 1.f - v * (1.0f / NCOLS);
        }
    }

    if (tid == 0) {
        int nr = 0, ns = 0;
        for (int bb = 0; bb < NB; ++bb) { int yb = y[bb]; nr += (yb == 0); ns += (yb == 1); }
        float lr = aR / (NCOLS * (float)(nr > 0 ? nr : 1));
        float ls = aS / (NCOLS * (float)(ns > 0 ? ns : 1));
        out[0] = lr + 0.5f * ls;                     // stc_loss
    }
}

// ---------------------------------------------------------------------------
// Host: bit-exact replication of np.random.default_rng(123).permutation(80)
// (SeedSequence -> PCG64 XSL-RR 128/64 -> random_interval Fisher-Yates)
// and of np.linspace(...).astype(int64) window-start subsampling.
// Pure CPU work, deterministic, graph-capture safe.
// ---------------------------------------------------------------------------
static void compute_params(Params& prm)
{
    // ---- numpy SeedSequence(123) ----
    const uint32_t INIT_A = 0x43b0d7e5u, MULT_A = 0x931e8875u;
    const uint32_t INIT_B = 0x8b51f9ddu, MULT_B = 0x58f38dedu;

    uint32_t hc = INIT_A;
    auto hashmix = [&](uint32_t v) -> uint32_t {
        v ^= hc; hc *= MULT_A; v *= hc; v ^= v >> 16; return v;
    };
    auto mix = [](uint32_t x, uint32_t y) -> uint32_t {
        uint32_t r = (x * 0xca01f9ddu) ^ (y * 0x4973f715u);
        r ^= r >> 16; return r;
    };

    uint32_t pool[4];
    const uint32_t entropy[1] = { 123u };
    for (int i = 0; i < 4; ++i) pool[i] = hashmix(i < 1 ? entropy[i] : 0u);
    for (int s = 0; s < 4; ++s)
        for (int d = 0; d < 4; ++d)
            if (s != d) pool[d] = mix(pool[d], hashmix(pool[s]));

    // generate_state(4, uint64) -> 8 uint32 words, LE-paired
    uint32_t w32[8];
    uint32_t hc2 = INIT_B;
    for (int i = 0; i < 8; ++i) {
        uint32_t v = pool[i & 3];
        v ^= hc2; hc2 *= MULT_B; v *= hc2; v ^= v >> 16;
        w32[i] = v;
    }
    uint64_t sd[4];
    for (int i = 0; i < 4; ++i)
        sd[i] = (uint64_t)w32[2 * i] | ((uint64_t)w32[2 * i + 1] << 32);

    // ---- PCG64 (setseq 128, XSL-RR output) ----
    typedef __uint128_t u128;
    const u128 MULT = ((u128)0x2360ed051fc65da4ULL << 64) | 0x4385df649fccf645ULL;
    u128 initstate = ((u128)sd[0] << 64) | sd[1];
    u128 initseq   = ((u128)sd[2] << 64) | sd[3];
    u128 state = 0, inc = (initseq << 1) | 1;
    state = state * MULT + inc;
    state += initstate;
    state = state * MULT + inc;

    bool has32 = false; uint32_t buf32 = 0;
    auto next64 = [&]() -> uint64_t {
        state = state * MULT + inc;                 // step THEN output
        uint64_t hi = (uint64_t)(state >> 64);
        uint64_t lo = (uint64_t)state;
        uint64_t x = hi ^ lo;
        unsigned rot = (unsigned)(state >> 122);    // top 6 bits
        return (x >> rot) | (x << ((64u - rot) & 63u));
    };
    auto next32 = [&]() -> uint32_t {
        if (has32) { has32 = false; return buf32; }
        uint64_t v = next64();
        has32 = true; buf32 = (uint32_t)(v >> 32);  // high half buffered
        return (uint32_t)v;                          // low half first
    };

    // ---- Generator.permutation(80): Fisher-Yates with random_interval ----
    int perm[NM];
    for (int i = 0; i < NM; ++i) perm[i] = i;
    for (int i = NM - 1; i >= 1; --i) {
        uint32_t mask = (uint32_t)i;
        mask |= mask >> 1; mask |= mask >> 2; mask |= mask >> 4;
        mask |= mask >> 8; mask |= mask >> 16;
        uint32_t j;
        do { j = next32() & mask; } while (j > (uint32_t)i);
        int tmp = perm[i]; perm[i] = perm[(int)j]; perm[(int)j] = tmp;
    }
    for (int i = 0; i < MSEL; ++i) prm.mel[i] = perm[i];

    // ---- window starts ----
    // hop_frames=3. w=5: full starts 0..1995 step 3 (666) -> linspace(0,665,64)
    //               w=10: full starts 0..1989 step 3 (664) -> linspace(0,663,64)
    {
        const double step = 665.0 / 63.0;
        for (int i = 0; i < 64; ++i) {
            long long sel = (i == 63) ? 665LL : (long long)((double)i * step);
            prm.start[i] = (int)(3LL * sel);
        }
    }
    {
        const double step = 663.0 / 63.0;
        for (int i = 0; i < 64; ++i) {
            long long sel = (i == 63) ? 663LL : (long long)((double)i * step);
            prm.start[64 + i] = (int)(3LL * sel);
        }
    }
}

extern "C" void kernel_launch(void* const* d_in, const int* in_sizes, int n_in,
                              void* d_out, int out_size, void* d_ws, size_t ws_size,
                              hipStream_t stream)
{
    const float* A   = (const float*)d_in[0];
    const float* P   = (const float*)d_in[1];
    const int*   y   = (const int*)d_in[2];
    const float* W1a = (const float*)d_in[3];
    const float* W2a = (const float*)d_in[4];
    const float* W1p = (const float*)d_in[5];
    const float* W2p = (const float*)d_in[6];
    float* out = (float*)d_out;
    (void)d_ws; (void)ws_size;   // harness workspace intentionally unused

    Params prm;
    compute_params(prm);

    asn_win_kernel<<<dim3(NBLK), dim3(128), 0, stream>>>(
        A, P, W1a, W2a, W1p, W2p, prm);
    asn_final_kernel<<<dim3(1), dim3(64), 0, stream>>>(y, out);
}

// Round 4
// 94.120 us; speedup vs baseline: 1.1285x; 1.0075x over previous
//
#include <hip/hip_runtime.h>
#include <stdint.h>

// Problem constants (from reference setup_inputs / module constants)
#define NB 32
#define NM 80
#define NT 2000
#define MSEL 16
#define NWIN 128         // 64 windows of w=5 + 64 windows of w=10
#define NBLK (NB * MSEL) // 512
#define NCOLS 2048.0f    // MSEL * 64 * 2 window lengths

struct Params {
    int mel[MSEL];
    int start[NWIN];     // [0:64) -> w=5 starts, [64:128) -> w=10 starts
};

// Module-static intermediate (NOT harness d_ws, which is poison-filled each
// iteration and would serialize us behind the 256-MiB fill).
// g_part4[blk] = (sumD_w5, sumR_w5, sumD_w10, sumR_w10) -- each wave writes
// its own float2 half; no cross-wave reduction, no barrier in the win kernel.
__device__ float4 g_part4[NBLK];

// ---------------------------------------------------------------------------
// Per-window gather + cosine accumulation. Loads first (max MLP, registers
// only -- full unroll keeps indices static), then accumulate in the exact
// FP order of previous rounds (bit-identical output).
// ---------------------------------------------------------------------------
template <int W>
__device__ inline void win_gather(const float* __restrict__ arow,
                                  const float* __restrict__ prow,
                                  int s, float4 c0, float4 c1,
                                  float& dot, float& na, float& npv)
{
    float av[W], pv[W];
    #pragma unroll
    for (int t = 0; t < W; ++t) { av[t] = arow[s + t]; pv[t] = prow[s + t]; }
    #pragma unroll
    for (int t = 0; t < W; ++t) {
        float a = av[t];
        float p = pv[t];
        float k  = (a >= 0.f) ? ((p >= 0.f) ? c0.w : c0.z)
                              : ((p >= 0.f) ? c0.y : c0.x);
        float sa = (a >= 0.f) ? c1.y : c1.x;
        float sp = (p >= 0.f) ? c1.w : c1.z;
        dot += a * p * k;
        na  += a * a * sa;
        npv += p * p * sp;
    }
}

// ---------------------------------------------------------------------------
// Kernel 1: one block per (b, mel_sel); NO LDS, NO __syncthreads.
// Diagnostic restructure (round 4): removes the staged-load convoy
// (16 KB burst -> vmcnt(0) -> barrier) entirely. Each thread gathers its
// own window directly from global (lines shared across the block via L1),
// each wave independently:
//   - collapses the 1->8->8 ReLU head into 8 scalars via shuffle reduce
//     (head(x)[o] = x * (x>=0 ? cap[o] : can[o]), cap/can = sign-split
//      W1*W2 column sums; K/norm coefs are the 8 pairwise dot products);
//   - computes its 64 windows' cosine distances;
//   - shuffle-reduces and writes its own float2 partial to g_part4[blk].
// ---------------------------------------------------------------------------
__global__ __launch_bounds__(128) void asn_win_kernel(
    const float* __restrict__ A, const float* __restrict__ P,
    const float* __restrict__ W1a, const float* __restrict__ W2a,
    const float* __restrict__ W1p, const float* __restrict__ W2p,
    Params prm)
{
    const int blk  = blockIdx.x;      // 0..511
    const int b    = blk >> 4;
    const int msi  = blk & 15;
    const int m    = prm.mel[msi];
    const int tid  = threadIdx.x;
    const int wv   = tid >> 6;        // 0: w=5 windows, 1: w=10 windows
    const int lane = tid & 63;

    const float* arow = A + ((size_t)b * NM + m) * NT;
    const float* prow = P + ((size_t)b * NM + m) * NT;

    // ---- per-wave head collapse (W arrays tiny, L2-hot broadcast) ---------
    const int c = lane & 7;                    // o = lane>>3, c = lane&7
    float w2a = W2a[lane];
    float w2p = W2p[lane];
    float w1a_l = (lane < 8) ? W1a[lane] : 0.f;
    float w1p_l = (lane < 8) ? W1p[lane] : 0.f;
    float wa = __shfl(w1a_l, c);               // W1[c] broadcast to all o-groups
    float wp = __shfl(w1p_l, c);

    float ta = wa * w2a, tp = wp * w2p;
    float cap = (wa > 0.f) ? ta : 0.f;
    float can = (wa < 0.f) ? ta : 0.f;
    float cqp = (wp > 0.f) ? tp : 0.f;
    float cqn = (wp < 0.f) ? tp : 0.f;

    #pragma unroll
    for (int off = 1; off < 8; off <<= 1) {    // sum over c within o-group
        cap += __shfl_xor(cap, off);
        can += __shfl_xor(can, off);
        cqp += __shfl_xor(cqp, off);
        cqn += __shfl_xor(cqn, off);
    }

    const bool rep = (c == 0);                 // per-o products, then sum over o
    float q0 = rep ? can * cqn : 0.f;   // knn
    float q1 = rep ? can * cqp : 0.f;   // knp
    float q2 = rep ? cap * cqn : 0.f;   // kpn
    float q3 = rep ? cap * cqp : 0.f;   // kpp
    float q4 = rep ? can * can : 0.f;   // san
    float q5 = rep ? cap * cap : 0.f;   // sap
    float q6 = rep ? cqn * cqn : 0.f;   // spn
    float q7 = rep ? cqp * cqp : 0.f;   // spp
    #pragma unroll
    for (int off = 8; off < 64; off <<= 1) {
        q0 += __shfl_xor(q0, off);
        q1 += __shfl_xor(q1, off);
        q2 += __shfl_xor(q2, off);
        q3 += __shfl_xor(q3, off);
        q4 += __shfl_xor(q4, off);
        q5 += __shfl_xor(q5, off);
        q6 += __shfl_xor(q6, off);
        q7 += __shfl_xor(q7, off);
    }
    // lanes with c!=0 hold zeros after the butterfly -> broadcast from lane 0
    q0 = __shfl(q0, 0); q1 = __shfl(q1, 0); q2 = __shfl(q2, 0); q3 = __shfl(q3, 0);
    q4 = __shfl(q4, 0); q5 = __shfl(q5, 0); q6 = __shfl(q6, 0); q7 = __shfl(q7, 0);
    const float4 c0 = make_float4(q0, q1, q2, q3);
    const float4 c1 = make_float4(q4, q5, q6, q7);

    // ---- one window per thread, gathered directly from global -------------
    const int s = prm.start[tid];
    float dot = 0.f, na = 0.f, npv = 0.f;
    if (wv == 0) win_gather<5> (arow, prow, s, c0, c1, dot, na, npv);
    else         win_gather<10>(arow, prow, s, c0, c1, dot, na, npv);

    float nu = fmaxf(sqrtf(na),  1e-12f);
    float nv = fmaxf(sqrtf(npv), 1e-12f);
    float dist = 1.f - dot / (nu * nv);
    float rd   = fmaxf(0.2f - dist, 0.f);   // relu(MARGIN - D)

    // wave-reduce 64 windows -> (sumD, sumR), write this wave's half
    float s1 = dist, s2 = rd;
    #pragma unroll
    for (int off = 32; off; off >>= 1) {
        s1 += __shfl_down(s1, off);
        s2 += __shfl_down(s2, off);
    }
    if (lane == 0) {
        ((float2*)&g_part4[blk])[wv] = make_float2(s1, s2);
    }
}

// ---------------------------------------------------------------------------
// Kernel 2: one wave (64 threads), no LDS, pure shuffle reduction.
// out[0]=stc_loss, out[1..32]=coh_score[b]. Cross-dispatch visibility of
// g_part4 is guaranteed by same-stream ordering (runtime cache maintenance).
// Per-block sum = wave0_half + wave1_half (same FP order as prior rounds).
// ---------------------------------------------------------------------------
__global__ __launch_bounds__(64) void asn_final_kernel(
    const int* __restrict__ y, float* __restrict__ out)
{
    const int tid = threadIdx.x;

    float aR = 0.f, aS = 0.f;
    float colsum[8];                 // per-lane contribution to coh per group
    #pragma unroll
    for (int r = 0; r < 8; ++r) {
        int k  = r * 64 + tid;       // 0..511
        int bb = k >> 4;
        float4 q = g_part4[k];
        float d  = q.x + q.z;        // wave0 + wave1, matches prior order
        float sv = q.y + q.w;
        if (y[bb] == 0) aR += d; else aS += sv;
        colsum[r] = d;
    }
    #pragma unroll
    for (int off = 32; off; off >>= 1) {
        aR += __shfl_down(aR, off);
        aS += __shfl_down(aS, off);
    }

    // coh_score: batch bb spans k in [16*bb, 16*bb+16); k = r*64 + tid ->
    // bb = r*4 + (tid>>4); reduce within each 16-lane group.
    #pragma unroll
    for (int r = 0; r < 8; ++r) {
        float v = colsum[r];
        #pragma unroll
        for (int off = 8; off; off >>= 1) v += __shfl_down(v, off);
        if ((tid & 15) == 0) {
            int bb = r * 4 + (tid >> 4);
            out[1 + bb] = 1.f - v * (1.0f / NCOLS);
        }
    }

    if (tid == 0) {
        int nr = 0, ns = 0;
        for (int bb = 0; bb < NB; ++bb) { int yb = y[bb]; nr += (yb == 0); ns += (yb == 1); }
        float lr = aR / (NCOLS * (float)(nr > 0 ? nr : 1));
        float ls = aS / (NCOLS * (float)(ns > 0 ? ns : 1));
        out[0] = lr + 0.5f * ls;                     // stc_loss
    }
}

// ---------------------------------------------------------------------------
// Host: bit-exact replication of np.random.default_rng(123).permutation(80)
// (SeedSequence -> PCG64 XSL-RR 128/64 -> random_interval Fisher-Yates)
// and of np.linspace(...).astype(int64) window-start subsampling.
// Pure CPU work, deterministic, graph-capture safe.
// ---------------------------------------------------------------------------
static void compute_params(Params& prm)
{
    // ---- numpy SeedSequence(123) ----
    const uint32_t INIT_A = 0x43b0d7e5u, MULT_A = 0x931e8875u;
    const uint32_t INIT_B = 0x8b51f9ddu, MULT_B = 0x58f38dedu;

    uint32_t hc = INIT_A;
    auto hashmix = [&](uint32_t v) -> uint32_t {
        v ^= hc; hc *= MULT_A; v *= hc; v ^= v >> 16; return v;
    };
    auto mix = [](uint32_t x, uint32_t y) -> uint32_t {
        uint32_t r = (x * 0xca01f9ddu) ^ (y * 0x4973f715u);
        r ^= r >> 16; return r;
    };

    uint32_t pool[4];
    const uint32_t entropy[1] = { 123u };
    for (int i = 0; i < 4; ++i) pool[i] = hashmix(i < 1 ? entropy[i] : 0u);
    for (int s = 0; s < 4; ++s)
        for (int d = 0; d < 4; ++d)
            if (s != d) pool[d] = mix(pool[d], hashmix(pool[s]));

    // generate_state(4, uint64) -> 8 uint32 words, LE-paired
    uint32_t w32[8];
    uint32_t hc2 = INIT_B;
    for (int i = 0; i < 8; ++i) {
        uint32_t v = pool[i & 3];
        v ^= hc2; hc2 *= MULT_B; v *= hc2; v ^= v >> 16;
        w32[i] = v;
    }
    uint64_t sd[4];
    for (int i = 0; i < 4; ++i)
        sd[i] = (uint64_t)w32[2 * i] | ((uint64_t)w32[2 * i + 1] << 32);

    // ---- PCG64 (setseq 128, XSL-RR output) ----
    typedef __uint128_t u128;
    const u128 MULT = ((u128)0x2360ed051fc65da4ULL << 64) | 0x4385df649fccf645ULL;
    u128 initstate = ((u128)sd[0] << 64) | sd[1];
    u128 initseq   = ((u128)sd[2] << 64) | sd[3];
    u128 state = 0, inc = (initseq << 1) | 1;
    state = state * MULT + inc;
    state += initstate;
    state = state * MULT + inc;

    bool has32 = false; uint32_t buf32 = 0;
    auto next64 = [&]() -> uint64_t {
        state = state * MULT + inc;                 // step THEN output
        uint64_t hi = (uint64_t)(state >> 64);
        uint64_t lo = (uint64_t)state;
        uint64_t x = hi ^ lo;
        unsigned rot = (unsigned)(state >> 122);    // top 6 bits
        return (x >> rot) | (x << ((64u - rot) & 63u));
    };
    auto next32 = [&]() -> uint32_t {
        if (has32) { has32 = false; return buf32; }
        uint64_t v = next64();
        has32 = true; buf32 = (uint32_t)(v >> 32);  // high half buffered
        return (uint32_t)v;                          // low half first
    };

    // ---- Generator.permutation(80): Fisher-Yates with random_interval ----
    int perm[NM];
    for (int i = 0; i < NM; ++i) perm[i] = i;
    for (int i = NM - 1; i >= 1; --i) {
        uint32_t mask = (uint32_t)i;
        mask |= mask >> 1; mask |= mask >> 2; mask |= mask >> 4;
        mask |= mask >> 8; mask |= mask >> 16;
        uint32_t j;
        do { j = next32() & mask; } while (j > (uint32_t)i);
        int tmp = perm[i]; perm[i] = perm[(int)j]; perm[(int)j] = tmp;
    }
    for (int i = 0; i < MSEL; ++i) prm.mel[i] = perm[i];

    // ---- window starts ----
    // hop_frames=3. w=5: full starts 0..1995 step 3 (666) -> linspace(0,665,64)
    //               w=10: full starts 0..1989 step 3 (664) -> linspace(0,663,64)
    {
        const double step = 665.0 / 63.0;
        for (int i = 0; i < 64; ++i) {
            long long sel = (i == 63) ? 665LL : (long long)((double)i * step);
            prm.start[i] = (int)(3LL * sel);
        }
    }
    {
        const double step = 663.0 / 63.0;
        for (int i = 0; i < 64; ++i) {
            long long sel = (i == 63) ? 663LL : (long long)((double)i * step);
            prm.start[64 + i] = (int)(3LL * sel);
        }
    }
}

extern "C" void kernel_launch(void* const* d_in, const int* in_sizes, int n_in,
                              void* d_out, int out_size, void* d_ws, size_t ws_size,
                              hipStream_t stream)
{
    const float* A   = (const float*)d_in[0];
    const float* P   = (const float*)d_in[1];
    const int*   y   = (const int*)d_in[2];
    const float* W1a = (const float*)d_in[3];
    const float* W2a = (const float*)d_in[4];
    const float* W1p = (const float*)d_in[5];
    const float* W2p = (const float*)d_in[6];
    float* out = (float*)d_out;
    (void)d_ws; (void)ws_size;   // harness workspace intentionally unused

    Params prm;
    compute_params(prm);

    asn_win_kernel<<<dim3(NBLK), dim3(128), 0, stream>>>(
        A, P, W1a, W2a, W1p, W2p, prm);
    asn_final_kernel<<<dim3(1), dim3(64), 0, stream>>>(y, out);
}